// Round 1
// baseline (609.520 us; speedup 1.0000x reference)
//
#include <hip/hip_runtime.h>
#include <stdint.h>
#include <stddef.h>

typedef __attribute__((ext_vector_type(8))) short bf16x8;
typedef __attribute__((ext_vector_type(4))) float f32x4;
typedef __attribute__((ext_vector_type(4))) unsigned int uint4v;

static __device__ __forceinline__ unsigned short f2bf(float f) {
  unsigned int u = __builtin_bit_cast(unsigned int, f);
  unsigned int r = (u + 0x7FFFu + ((u >> 16) & 1u)) >> 16;
  return (unsigned short)r;
}

static __device__ __forceinline__ void gld16(const void* g, void* l) {
  __builtin_amdgcn_global_load_lds(
      (const __attribute__((address_space(1))) void*)g,
      (__attribute__((address_space(3))) void*)l, 16, 0, 0);
}

// ---------- weight transpose + cast: src [R][C] f32 -> dst [C][R] bf16 ----------
__global__ void transpose_cast(const float* __restrict__ src,
                               unsigned short* __restrict__ dst, int R, int C) {
  __shared__ float tile[32][33];
  int c0 = blockIdx.x * 32, r0 = blockIdx.y * 32;
  int tx = threadIdx.x, ty = threadIdx.y;  // (32, 8)
  #pragma unroll
  for (int i = 0; i < 32; i += 8)
    tile[ty + i][tx] = src[(size_t)(r0 + ty + i) * C + c0 + tx];
  __syncthreads();
  #pragma unroll
  for (int i = 0; i < 32; i += 8)
    dst[(size_t)(c0 + ty + i) * R + r0 + tx] = f2bf(tile[tx][ty + i]);
}

// ---------- block reduce ----------
static __device__ __forceinline__ float blksum256(float v, float* sb) {
  #pragma unroll
  for (int o = 32; o > 0; o >>= 1) v += __shfl_down(v, o, 64);
  int lane = threadIdx.x & 63, w = threadIdx.x >> 6;
  __syncthreads();
  if (lane == 0) sb[w] = v;
  __syncthreads();
  return sb[0] + sb[1] + sb[2] + sb[3];
}

// ---------- LayerNorm (MODE 0: write to shifted/window-partitioned rows; MODE 1: identity) ----------
template <int MODE>
__global__ __launch_bounds__(256) void ln_kernel(const float* __restrict__ x,
                                                 const float* __restrict__ gg,
                                                 const float* __restrict__ bb,
                                                 unsigned short* __restrict__ out) {
  __shared__ float sb[4];
  const int d = blockIdx.x;  // dest row (window order for MODE 0)
  size_t srow;
  if (MODE == 0) {
    int b = d >> 7, wid = (d >> 4) & 7, tok = d & 15;
    int oh = (((wid >> 2) << 2) + (tok >> 2) + 2) & 7;
    int ow = (((wid & 3) << 2) + (tok & 3) + 2) & 15;
    srow = (size_t)(b << 7) + oh * 16 + ow;
  } else {
    srow = d;
  }
  const float* xr = x + srow * 768;
  const int t = threadIdx.x;
  float v0 = xr[t], v1 = xr[t + 256], v2 = xr[t + 512];
  float mean = blksum256(v0 + v1 + v2, sb) * (1.0f / 768.0f);
  float d0 = v0 - mean, d1 = v1 - mean, d2 = v2 - mean;
  float var = blksum256(d0 * d0 + d1 * d1 + d2 * d2, sb) * (1.0f / 768.0f);
  float rstd = rsqrtf(var + 1e-5f);
  size_t o = (size_t)d * 768;
  out[o + t]       = f2bf(d0 * rstd * gg[t] + bb[t]);
  out[o + t + 256] = f2bf(d1 * rstd * gg[t + 256] + bb[t + 256]);
  out[o + t + 512] = f2bf(d2 * rstd * gg[t + 512] + bb[t + 512]);
}

// ---------- GEMM: C[M][N] = A[M][K] @ BT[N][K]^T + bias, with fused epilogues ----------
// EPI 0: +bias -> bf16 (qkv)
// EPI 1: +bias, window-reverse+unshift scatter, +resid(x) -> fp32 xr (proj)
// EPI 2: +bias, exact gelu -> bf16 (fc1)
// EPI 3: +bias, +resid(xr) -> fp32 out (fc2)
template <int EPI>
__global__ __launch_bounds__(256) void gemm_bt(const unsigned short* __restrict__ A,
                                               const unsigned short* __restrict__ BT,
                                               const float* __restrict__ bias,
                                               float* __restrict__ outF,
                                               unsigned short* __restrict__ outB,
                                               const float* __restrict__ resid,
                                               int M, int N, int K) {
  __shared__ __align__(16) unsigned short As[128 * 32];
  __shared__ __align__(16) unsigned short Bs[128 * 32];
  const int tid = threadIdx.x;
  const int lane = tid & 63, wv = tid >> 6;
  const int m0 = blockIdx.y << 7, n0 = blockIdx.x << 7;
  const int wr = (wv >> 1) << 6, wc = (wv & 1) << 6;
  const int fr = lane & 15, kg = (lane >> 4) << 3;

  f32x4 acc[4][4];
  #pragma unroll
  for (int i = 0; i < 4; ++i)
    #pragma unroll
    for (int j = 0; j < 4; ++j) acc[i][j] = (f32x4){0.f, 0.f, 0.f, 0.f};

  const int l4 = lane >> 2;          // row within 16-row staging chunk
  const int lb = (lane & 3) << 3;    // element offset (8 bf16 = 16B)
  const unsigned short* gA = A + (size_t)(m0 + wv * 32 + l4) * K + lb;
  const unsigned short* gB = BT + (size_t)(n0 + wv * 32 + l4) * K + lb;
  char* lA = (char*)As + wv * 32 * 64;  // wave-uniform LDS base; HW adds lane*16
  char* lB = (char*)Bs + wv * 32 * 64;

  for (int k0 = 0; k0 < K; k0 += 32) {
    gld16(gA + k0, lA);
    gld16(gA + (size_t)16 * K + k0, lA + 1024);
    gld16(gB + k0, lB);
    gld16(gB + (size_t)16 * K + k0, lB + 1024);
    __syncthreads();
    bf16x8 af[4], bfr[4];
    #pragma unroll
    for (int m = 0; m < 4; ++m)
      af[m] = *(const bf16x8*)&As[(wr + m * 16 + fr) * 32 + kg];
    #pragma unroll
    for (int n = 0; n < 4; ++n)
      bfr[n] = *(const bf16x8*)&Bs[(wc + n * 16 + fr) * 32 + kg];
    #pragma unroll
    for (int m = 0; m < 4; ++m)
      #pragma unroll
      for (int n = 0; n < 4; ++n)
        acc[m][n] = __builtin_amdgcn_mfma_f32_16x16x32_bf16(af[m], bfr[n], acc[m][n], 0, 0, 0);
    __syncthreads();
  }

  #pragma unroll
  for (int mi = 0; mi < 4; ++mi) {
    #pragma unroll
    for (int ni = 0; ni < 4; ++ni) {
      const int col = n0 + wc + ni * 16 + fr;
      const float bc = bias[col];
      #pragma unroll
      for (int i = 0; i < 4; ++i) {
        const int row = m0 + wr + mi * 16 + ((lane >> 4) << 2) + i;
        float v = acc[mi][ni][i] + bc;
        if (EPI == 0) {
          outB[(size_t)row * N + col] = f2bf(v);
        } else if (EPI == 1) {
          int b = row >> 7, wid = (row >> 4) & 7, tok = row & 15;
          int oh = (((wid >> 2) << 2) + (tok >> 2) + 2) & 7;
          int ow = (((wid & 3) << 2) + (tok & 3) + 2) & 15;
          size_t di = ((size_t)(b << 7) + oh * 16 + ow) * 768 + col;
          outF[di] = v + resid[di];
        } else if (EPI == 2) {
          float g = 0.5f * v * (1.0f + erff(v * 0.70710678118f));
          outB[(size_t)row * N + col] = f2bf(g);
        } else {
          size_t di = (size_t)row * N + col;
          outF[di] = v + resid[di];
        }
      }
    }
  }
}

// ---------- window attention: one wave per (window, head) ----------
__global__ __launch_bounds__(64) void attn_win(const unsigned short* __restrict__ qkv,
                                               const float* __restrict__ rel_table,
                                               unsigned short* __restrict__ o) {
  __shared__ __align__(16) unsigned short q_s[16 * 64];
  __shared__ __align__(16) unsigned short k_s[16 * 64];
  __shared__ __align__(16) unsigned short vt_s[64 * 32];  // [d][m], m padded to 32
  __shared__ __align__(16) unsigned short p_s[16 * 32];   // [n][m], m padded to 32
  const int bid = blockIdx.x;
  const int win = bid / 12;
  const int head = bid - win * 12;
  const int wid = win & 7;
  const int lane = threadIdx.x;
  const unsigned short* gq =
      qkv + (size_t)win * 16 * 2304 + head * 64 + (size_t)(lane >> 2) * 2304 + ((lane & 3) << 4);
  const int t = lane >> 2, d0 = (lane & 3) << 4;
  *(uint4v*)&q_s[t * 64 + d0]     = *(const uint4v*)(gq);
  *(uint4v*)&q_s[t * 64 + d0 + 8] = *(const uint4v*)(gq + 8);
  *(uint4v*)&k_s[t * 64 + d0]     = *(const uint4v*)(gq + 768);
  *(uint4v*)&k_s[t * 64 + d0 + 8] = *(const uint4v*)(gq + 776);
  unsigned short vv[16];
  *(uint4v*)&vv[0] = *(const uint4v*)(gq + 1536);
  *(uint4v*)&vv[8] = *(const uint4v*)(gq + 1544);
  #pragma unroll
  for (int e = 0; e < 16; ++e) vt_s[(d0 + e) * 32 + t] = vv[e];
  #pragma unroll
  for (int e = 0; e < 16; ++e) vt_s[lane * 32 + 16 + e] = 0;  // K-pad of V
  if (lane < 16) {
    #pragma unroll
    for (int e = 0; e < 16; ++e) p_s[lane * 32 + 16 + e] = 0;  // K-pad of P
  }
  __syncthreads();

  const int fr = lane & 15, kg = (lane >> 4) << 3;
  bf16x8 qa0 = *(const bf16x8*)&q_s[fr * 64 + kg];
  bf16x8 qa1 = *(const bf16x8*)&q_s[fr * 64 + 32 + kg];
  bf16x8 ka0 = *(const bf16x8*)&k_s[fr * 64 + kg];
  bf16x8 ka1 = *(const bf16x8*)&k_s[fr * 64 + 32 + kg];
  f32x4 s = (f32x4){0.f, 0.f, 0.f, 0.f};
  s = __builtin_amdgcn_mfma_f32_16x16x32_bf16(qa0, ka0, s, 0, 0, 0);
  s = __builtin_amdgcn_mfma_f32_16x16x32_bf16(qa1, ka1, s, 0, 0, 0);
  // S[n][m]: n = (lane>>4)*4 + i, m = fr

  const int wh = wid >> 2, wwc = wid & 3;
  const int rj = fr >> 2, cj = fr & 3;
  const int rowm = wh * 4 + rj, colm = wwc * 4 + cj;
  const int rgm = (rowm < 4 ? 0 : (rowm < 6 ? 1 : 2)) * 3 +
                  (colm < 12 ? 0 : (colm < 14 ? 1 : 2));
  float p[4];
  #pragma unroll
  for (int i = 0; i < 4; ++i) {
    int n = ((lane >> 4) << 2) + i;
    int ri = n >> 2, ci = n & 3;
    int rown = wh * 4 + ri, coln = wwc * 4 + ci;
    int rgn = (rown < 4 ? 0 : (rown < 6 ? 1 : 2)) * 3 +
              (coln < 12 ? 0 : (coln < 14 ? 1 : 2));
    float bias = rel_table[(size_t)((ri - rj + 3) * 7 + (ci - cj + 3)) * 12 + head];
    p[i] = s[i] * 0.125f + bias + (rgn != rgm ? -100.0f : 0.0f);
  }
  float mx[4] = {p[0], p[1], p[2], p[3]};
  #pragma unroll
  for (int off = 8; off > 0; off >>= 1)
    #pragma unroll
    for (int i = 0; i < 4; ++i) mx[i] = fmaxf(mx[i], __shfl_xor(mx[i], off, 64));
  float sm[4];
  #pragma unroll
  for (int i = 0; i < 4; ++i) { p[i] = __expf(p[i] - mx[i]); sm[i] = p[i]; }
  #pragma unroll
  for (int off = 8; off > 0; off >>= 1)
    #pragma unroll
    for (int i = 0; i < 4; ++i) sm[i] += __shfl_xor(sm[i], off, 64);
  #pragma unroll
  for (int i = 0; i < 4; ++i)
    p_s[(((lane >> 4) << 2) + i) * 32 + fr] = f2bf(p[i] / sm[i]);
  __syncthreads();

  bf16x8 pa = *(const bf16x8*)&p_s[fr * 32 + kg];
  const f32x4 oz = (f32x4){0.f, 0.f, 0.f, 0.f};
  #pragma unroll
  for (int c = 0; c < 4; ++c) {
    bf16x8 vb = *(const bf16x8*)&vt_s[(c * 16 + fr) * 32 + kg];
    f32x4 oa = __builtin_amdgcn_mfma_f32_16x16x32_bf16(pa, vb, oz, 0, 0, 0);
    #pragma unroll
    for (int i = 0; i < 4; ++i) {
      int n = ((lane >> 4) << 2) + i;
      o[((size_t)win * 16 + n) * 768 + head * 64 + c * 16 + fr] = f2bf(oa[i]);
    }
  }
}

extern "C" void kernel_launch(void* const* d_in, const int* in_sizes, int n_in,
                              void* d_out, int out_size, void* d_ws, size_t ws_size,
                              hipStream_t stream) {
  const float* x      = (const float*)d_in[0];
  const float* ln1_g  = (const float*)d_in[1];
  const float* ln1_b  = (const float*)d_in[2];
  const float* qkv_w  = (const float*)d_in[3];
  const float* qkv_b  = (const float*)d_in[4];
  const float* proj_w = (const float*)d_in[5];
  const float* proj_b = (const float*)d_in[6];
  const float* rel_t  = (const float*)d_in[7];
  const float* ln2_g  = (const float*)d_in[8];
  const float* ln2_b  = (const float*)d_in[9];
  const float* fc1_w  = (const float*)d_in[10];
  const float* fc1_b  = (const float*)d_in[11];
  const float* fc2_w  = (const float*)d_in[12];
  const float* fc2_b  = (const float*)d_in[13];
  float* out = (float*)d_out;

  char* ws = (char*)d_ws;
  // region A (50,331,648 B): hw -> o -> y  (all [32768][768] bf16, sequential reuse)
  unsigned short* wsA = (unsigned short*)(ws);
  // region B: qkv bf16 [32768][2304] (150,994,944 B); later xr fp32 [32768][768] (100,663,296 B)
  unsigned short* qkvb = (unsigned short*)(ws + 50331648);
  float* xr = (float*)(ws + 50331648);
  // region C: h1 bf16 [32768][1024] (67,108,864 B)
  unsigned short* h1 = (unsigned short*)(ws + 201326592);
  // bf16 transposed weights
  unsigned short* qkv_wT = (unsigned short*)(ws + 268435456);  // [2304][768]
  unsigned short* proj_wT = (unsigned short*)(ws + 271974400); // [768][768]
  unsigned short* fc1_wT = (unsigned short*)(ws + 273154048);  // [1024][768]
  unsigned short* fc2_wT = (unsigned short*)(ws + 274726912);  // [768][1024]

  dim3 tb(32, 8);
  transpose_cast<<<dim3(2304 / 32, 768 / 32), tb, 0, stream>>>(qkv_w, qkv_wT, 768, 2304);
  transpose_cast<<<dim3(768 / 32, 768 / 32), tb, 0, stream>>>(proj_w, proj_wT, 768, 768);
  transpose_cast<<<dim3(1024 / 32, 768 / 32), tb, 0, stream>>>(fc1_w, fc1_wT, 768, 1024);
  transpose_cast<<<dim3(768 / 32, 1024 / 32), tb, 0, stream>>>(fc2_w, fc2_wT, 1024, 768);

  ln_kernel<0><<<32768, 256, 0, stream>>>(x, ln1_g, ln1_b, wsA);                 // hw
  gemm_bt<0><<<dim3(18, 256), 256, 0, stream>>>(wsA, qkv_wT, qkv_b, nullptr, qkvb,
                                                nullptr, 32768, 2304, 768);      // qkv
  attn_win<<<24576, 64, 0, stream>>>(qkvb, rel_t, wsA);                          // o
  gemm_bt<1><<<dim3(6, 256), 256, 0, stream>>>(wsA, proj_wT, proj_b, xr, nullptr,
                                               x, 32768, 768, 768);              // xr = x + proj(o)
  ln_kernel<1><<<32768, 256, 0, stream>>>(xr, ln2_g, ln2_b, wsA);                // y
  gemm_bt<2><<<dim3(8, 256), 256, 0, stream>>>(wsA, fc1_wT, fc1_b, nullptr, h1,
                                               nullptr, 32768, 1024, 768);       // h1 = gelu(...)
  gemm_bt<3><<<dim3(6, 256), 256, 0, stream>>>(h1, fc2_wT, fc2_b, out, nullptr,
                                               xr, 32768, 768, 1024);            // out = xr + fc2(h1)
}